// Round 5
// baseline (216.829 us; speedup 1.0000x reference)
//
#include <hip/hip_runtime.h>

// ContrastiveLoss: loss = sum_n [ log(sum_j exp(2*<ne_n,ne_j>)) - 2*<ne_n,nt_n> ] / (2N)
// N=8192, D=512.
// R4: LDS-FREE GEMM. MFMA fragments loaded directly global->VGPR
//     (A[m=lane&15][k=quad*8+j] per verified 16x16x32 bf16 operand layout);
//     no __syncthreads in the K-loop -> no vmcnt(0) barrier drain (the R1-R3
//     plateau). Full 16-iter unroll, immediate-offset dwordx4 loads, 2-deep
//     register pipeline. XCD-partitioned triangular schedule kept from R3
//     (FETCH_SIZE 98->21 MB). __launch_bounds__(256,3) caps VGPR hoisting.

typedef __attribute__((ext_vector_type(8))) short short8;
typedef __attribute__((ext_vector_type(4))) float floatx4;

#define N 8192
#define D 512
#define BK 32            // k-step in bf16 elems
#define NIT (D / BK)     // 16 k-iterations
#define NT 64            // 128-row tiles per dim

__device__ __forceinline__ unsigned short f2bf(float f) {
    unsigned int u = __float_as_uint(f);
    unsigned int r = u + 0x7fffu + ((u >> 16) & 1u);   // round-to-nearest-even
    return (unsigned short)(r >> 16);
}

// Per-XCD segment tables: 5 segments each = [diag36, off64, off64, off64, half32].
__device__ __constant__ unsigned char seg_ga[8][5] = {
    {0,0,0,0,0},{1,1,1,1,0},{2,2,2,2,2},{3,3,3,3,2},
    {4,0,0,0,4},{5,1,1,1,4},{6,2,3,4,6},{7,4,5,5,6}};
__device__ __constant__ unsigned char seg_gb[8][5] = {
    {0,2,3,4,1},{1,2,3,4,1},{2,5,6,7,3},{3,5,6,7,3},
    {4,5,6,7,5},{5,5,6,7,5},{6,4,4,6,7},{7,7,6,7,7}};

__global__ __launch_bounds__(256) void k_norm(const float* __restrict__ emb,
                                              const float* __restrict__ tgt,
                                              unsigned short* __restrict__ neb,
                                              float* __restrict__ pos,
                                              float* __restrict__ out) {
    if (blockIdx.x == 0 && threadIdx.x == 0) *out = 0.0f;   // replaces memset dispatch
    int wave = threadIdx.x >> 6;
    int lane = threadIdx.x & 63;
    int row  = blockIdx.x * 4 + wave;          // one wave per row
    const float4* e4 = (const float4*)(emb + (size_t)row * D) + lane * 2;
    const float4* t4 = (const float4*)(tgt + (size_t)row * D) + lane * 2;
    float4 e0 = e4[0], e1 = e4[1];
    float4 t0 = t4[0], t1 = t4[1];
    float ee = e0.x*e0.x + e0.y*e0.y + e0.z*e0.z + e0.w*e0.w
             + e1.x*e1.x + e1.y*e1.y + e1.z*e1.z + e1.w*e1.w;
    float tt = t0.x*t0.x + t0.y*t0.y + t0.z*t0.z + t0.w*t0.w
             + t1.x*t1.x + t1.y*t1.y + t1.z*t1.z + t1.w*t1.w;
    float et = e0.x*t0.x + e0.y*t0.y + e0.z*t0.z + e0.w*t0.w
             + e1.x*t1.x + e1.y*t1.y + e1.z*t1.z + e1.w*t1.w;
    #pragma unroll
    for (int off = 1; off < 64; off <<= 1) {
        ee += __shfl_xor(ee, off);
        tt += __shfl_xor(tt, off);
        et += __shfl_xor(et, off);
    }
    float se = fmaxf(sqrtf(ee), 1e-12f);
    float st = fmaxf(sqrtf(tt), 1e-12f);
    if (lane == 0) pos[row] = et / (se * st);
    float inv = 1.0f / se;
    unsigned short v0 = f2bf(e0.x*inv), v1 = f2bf(e0.y*inv), v2 = f2bf(e0.z*inv), v3 = f2bf(e0.w*inv);
    unsigned short v4 = f2bf(e1.x*inv), v5 = f2bf(e1.y*inv), v6 = f2bf(e1.z*inv), v7 = f2bf(e1.w*inv);
    uint4 pk;
    pk.x = (unsigned)v0 | ((unsigned)v1 << 16);
    pk.y = (unsigned)v2 | ((unsigned)v3 << 16);
    pk.z = (unsigned)v4 | ((unsigned)v5 << 16);
    pk.w = (unsigned)v6 | ((unsigned)v7 << 16);
    ((uint4*)(neb + (size_t)row * D))[lane] = pk;
}

__global__ __launch_bounds__(256, 3) void k_gemm(const unsigned short* __restrict__ neb,
                                                 float* __restrict__ partial) {
    // XCD-partitioned decode: x = XCD stream, s = sequence within stream
    const int x = (int)(blockIdx.x & 7);
    int s = (int)(blockIdx.x >> 3);          // 0..259
    int seg, u;
    if (s < 36)       { seg = 0; u = s; }
    else if (s < 100) { seg = 1; u = s - 36; }
    else if (s < 164) { seg = 2; u = s - 100; }
    else if (s < 228) { seg = 3; u = s - 164; }
    else              { seg = 4; u = s - 228 + ((x & 1) ? 32 : 0); }
    const int ga = seg_ga[x][seg], gb = seg_gb[x][seg];
    int bi, bj;
    if (seg == 0) {                           // diag supertile: tri decode in 8x8
        int di = 0;
        while (u >= 8 - di) { u -= 8 - di; ++di; }
        bi = ga * 8 + di; bj = gb * 8 + di + u;
    } else {
        bi = ga * 8 + (u >> 3); bj = gb * 8 + (u & 7);
    }

    const int tid  = threadIdx.x;
    const int i0   = bi * 128, j0 = bj * 128;
    const int wave = tid >> 6, lane = tid & 63;
    const int wrow = wave >> 1, wcol = wave & 1;   // 2x2 waves, each 64x64
    const int m16  = lane & 15, quad = lane >> 4;

    // fragment base pointers: A[m=lane&15][k=quad*8+j] operand layout
    const unsigned short* pa[4];
    const unsigned short* pb[4];
    #pragma unroll
    for (int t = 0; t < 4; ++t) {
        pa[t] = neb + (size_t)(i0 + wrow * 64 + t * 16 + m16) * D + quad * 8;
        pb[t] = neb + (size_t)(j0 + wcol * 64 + t * 16 + m16) * D + quad * 8;
    }

    floatx4 zero = {0.f, 0.f, 0.f, 0.f};
    floatx4 acc[4][4];
    #pragma unroll
    for (int a = 0; a < 4; ++a)
        #pragma unroll
        for (int b = 0; b < 4; ++b) acc[a][b] = zero;

    short8 ca[4], cb[4], na[4], nb[4];
    #pragma unroll
    for (int t = 0; t < 4; ++t) { ca[t] = *(const short8*)(pa[t]); cb[t] = *(const short8*)(pb[t]); }

    #pragma unroll
    for (int it = 0; it < NIT; ++it) {
        if (it + 1 < NIT) {
            const int kn = (it + 1) * BK;
            #pragma unroll
            for (int t = 0; t < 4; ++t) {
                na[t] = *(const short8*)(pa[t] + kn);
                nb[t] = *(const short8*)(pb[t] + kn);
            }
        }
        #pragma unroll
        for (int ti = 0; ti < 4; ++ti)
            #pragma unroll
            for (int tj = 0; tj < 4; ++tj)
                acc[ti][tj] = __builtin_amdgcn_mfma_f32_16x16x32_bf16(ca[ti], cb[tj], acc[ti][tj], 0, 0, 0);
        #pragma unroll
        for (int t = 0; t < 4; ++t) { ca[t] = na[t]; cb[t] = nb[t]; }
    }

    // row-sums: exp(2*c) summed over this block's 128 cols -> slot bj*2+wcol
    const int prow = bj * 2 + wcol;
    #pragma unroll
    for (int ti = 0; ti < 4; ++ti) {
        #pragma unroll
        for (int r = 0; r < 4; ++r) {
            float ss = 0.f;
            #pragma unroll
            for (int tj = 0; tj < 4; ++tj) ss += __expf(2.0f * acc[ti][tj][r]);
            #pragma unroll
            for (int off = 1; off < 16; off <<= 1) ss += __shfl_xor(ss, off);
            if (m16 == 0) {
                int rowg = i0 + wrow * 64 + ti * 16 + quad * 4 + r;
                partial[(size_t)prow * N + rowg] = ss;
            }
        }
    }
    // col-sums (symmetry: = row-sums of skipped tile (bj,bi)) -> slot bi*2+wrow
    if (bi < bj) {
        const int pcol = bi * 2 + wrow;
        #pragma unroll
        for (int tj = 0; tj < 4; ++tj) {
            float ss = 0.f;
            #pragma unroll
            for (int ti = 0; ti < 4; ++ti) {
                #pragma unroll
                for (int r = 0; r < 4; ++r) ss += __expf(2.0f * acc[ti][tj][r]);
            }
            ss += __shfl_xor(ss, 16);
            ss += __shfl_xor(ss, 32);
            if (quad == 0) {
                int colg = j0 + wcol * 64 + tj * 16 + m16;
                partial[(size_t)pcol * N + colg] = ss;
            }
        }
    }
}

__global__ __launch_bounds__(256) void k_final(const float* __restrict__ partial,
                                               const float* __restrict__ pos,
                                               float* __restrict__ out) {
    int tid = threadIdx.x;
    int row = blockIdx.x * 64 + (tid >> 2);
    int sub = tid & 3;
    float S = 0.f;
    #pragma unroll
    for (int i = 0; i < 32; ++i) S += partial[(size_t)(sub + i * 4) * N + row];
    S += __shfl_xor(S, 1);
    S += __shfl_xor(S, 2);
    float val = (sub == 0) ? (logf(S) - 2.0f * pos[row]) : 0.0f;
    #pragma unroll
    for (int off = 4; off < 64; off <<= 1) val += __shfl_xor(val, off);
    if ((tid & 63) == 0) atomicAdd(out, val * (1.0f / (2.0f * N)));
}

extern "C" void kernel_launch(void* const* d_in, const int* in_sizes, int n_in,
                              void* d_out, int out_size, void* d_ws, size_t ws_size,
                              hipStream_t stream) {
    const float* emb = (const float*)d_in[0];
    const float* tgt = (const float*)d_in[1];
    unsigned short* neb = (unsigned short*)d_ws;                                 // 8 MB bf16 ne
    float* pos     = (float*)((char*)d_ws + (size_t)N * D * 2);                  // 32 KB
    float* partial = (float*)((char*)d_ws + (size_t)N * D * 2 + (size_t)N * 4);  // 4 MB
    float* out = (float*)d_out;

    k_norm<<<N / 4, 256, 0, stream>>>(emb, tgt, neb, pos, out);
    k_gemm<<<NT * (NT + 1) / 2, 256, 0, stream>>>(neb, partial);
    k_final<<<N / 64, 256, 0, stream>>>(partial, pos, out);
}

// Round 6
// 138.304 us; speedup vs baseline: 1.5678x; 1.5678x over previous
//
#include <hip/hip_runtime.h>

// ContrastiveLoss: loss = sum_n [ log(sum_j exp(2*<ne_n,ne_j>)) - 2*<ne_n,nt_n> ] / (2N)
// N=8192, D=512.
// R5: PRE-SHUFFLED OPERAND LAYOUT + barrier-free GEMM.
//     k_norm writes ne in MFMA-fragment-tiled order: 1 KB block per
//     (16 rows x 32 k) tile, within-block offset = lane*16 for
//     lane = quad*16 + m16 (the verified 16x16x32 bf16 operand mapping).
//     k_gemm then loads fragments with single coalesced global_load_dwordx4
//     (contiguous 1 KB per wave) -- no LDS, no __syncthreads, no vmcnt(0)
//     drain (the R1-R3 plateau), no 64-line scatter (the R4 disaster).
//     XCD-partitioned triangular schedule kept from R3.

typedef __attribute__((ext_vector_type(8))) short short8;
typedef __attribute__((ext_vector_type(4))) float floatx4;

#define N 8192
#define D 512
#define BK 32            // k-step in bf16 elems
#define NIT (D / BK)     // 16 k-iterations
#define NT 64            // 128-row tiles per dim

__device__ __forceinline__ unsigned short f2bf(float f) {
    unsigned int u = __float_as_uint(f);
    unsigned int r = u + 0x7fffu + ((u >> 16) & 1u);   // round-to-nearest-even
    return (unsigned short)(r >> 16);
}

// Per-XCD segment tables: 5 segments each = [diag36, off64, off64, off64, half32].
__device__ __constant__ unsigned char seg_ga[8][5] = {
    {0,0,0,0,0},{1,1,1,1,0},{2,2,2,2,2},{3,3,3,3,2},
    {4,0,0,0,4},{5,1,1,1,4},{6,2,3,4,6},{7,4,5,5,6}};
__device__ __constant__ unsigned char seg_gb[8][5] = {
    {0,2,3,4,1},{1,2,3,4,1},{2,5,6,7,3},{3,5,6,7,3},
    {4,5,6,7,5},{5,5,6,7,5},{6,4,4,6,7},{7,7,6,7,7}};

__global__ __launch_bounds__(256) void k_norm(const float* __restrict__ emb,
                                              const float* __restrict__ tgt,
                                              unsigned short* __restrict__ neb,
                                              float* __restrict__ pos,
                                              float* __restrict__ out) {
    if (blockIdx.x == 0 && threadIdx.x == 0) *out = 0.0f;   // replaces memset dispatch
    int wave = threadIdx.x >> 6;
    int lane = threadIdx.x & 63;
    int row  = blockIdx.x * 4 + wave;          // one wave per row; lane holds k=lane*8..+8
    const float4* e4 = (const float4*)(emb + (size_t)row * D) + lane * 2;
    const float4* t4 = (const float4*)(tgt + (size_t)row * D) + lane * 2;
    float4 e0 = e4[0], e1 = e4[1];
    float4 t0 = t4[0], t1 = t4[1];
    float ee = e0.x*e0.x + e0.y*e0.y + e0.z*e0.z + e0.w*e0.w
             + e1.x*e1.x + e1.y*e1.y + e1.z*e1.z + e1.w*e1.w;
    float tt = t0.x*t0.x + t0.y*t0.y + t0.z*t0.z + t0.w*t0.w
             + t1.x*t1.x + t1.y*t1.y + t1.z*t1.z + t1.w*t1.w;
    float et = e0.x*t0.x + e0.y*t0.y + e0.z*t0.z + e0.w*t0.w
             + e1.x*t1.x + e1.y*t1.y + e1.z*t1.z + e1.w*t1.w;
    #pragma unroll
    for (int off = 1; off < 64; off <<= 1) {
        ee += __shfl_xor(ee, off);
        tt += __shfl_xor(tt, off);
        et += __shfl_xor(et, off);
    }
    float se = fmaxf(sqrtf(ee), 1e-12f);
    float st = fmaxf(sqrtf(tt), 1e-12f);
    if (lane == 0) pos[row] = et / (se * st);
    float inv = 1.0f / se;
    unsigned short v0 = f2bf(e0.x*inv), v1 = f2bf(e0.y*inv), v2 = f2bf(e0.z*inv), v3 = f2bf(e0.w*inv);
    unsigned short v4 = f2bf(e1.x*inv), v5 = f2bf(e1.y*inv), v6 = f2bf(e1.z*inv), v7 = f2bf(e1.w*inv);
    uint4 pk;
    pk.x = (unsigned)v0 | ((unsigned)v1 << 16);
    pk.y = (unsigned)v2 | ((unsigned)v3 << 16);
    pk.z = (unsigned)v4 | ((unsigned)v5 << 16);
    pk.w = (unsigned)v6 | ((unsigned)v7 << 16);
    // shuffled store: block (row>>4, k-chunk lane>>2), within-block
    // lane' = (lane&3)*16 + (row&15)  [quad' = chunk-local k/8, m' = row&15]
    size_t u4idx = ((size_t)(row >> 4) * 16 + (lane >> 2)) * 64
                 + (size_t)(lane & 3) * 16 + (row & 15);
    ((uint4*)neb)[u4idx] = pk;
}

__global__ __launch_bounds__(256, 3) void k_gemm(const unsigned short* __restrict__ neb,
                                                 float* __restrict__ partial) {
    // XCD-partitioned decode: x = XCD stream, s = sequence within stream
    const int x = (int)(blockIdx.x & 7);
    int s = (int)(blockIdx.x >> 3);          // 0..259
    int seg, u;
    if (s < 36)       { seg = 0; u = s; }
    else if (s < 100) { seg = 1; u = s - 36; }
    else if (s < 164) { seg = 2; u = s - 100; }
    else if (s < 228) { seg = 3; u = s - 164; }
    else              { seg = 4; u = s - 228 + ((x & 1) ? 32 : 0); }
    const int ga = seg_ga[x][seg], gb = seg_gb[x][seg];
    int bi, bj;
    if (seg == 0) {                           // diag supertile: tri decode in 8x8
        int di = 0;
        while (u >= 8 - di) { u -= 8 - di; ++di; }
        bi = ga * 8 + di; bj = gb * 8 + di + u;
    } else {
        bi = ga * 8 + (u >> 3); bj = gb * 8 + (u & 7);
    }

    const int tid  = threadIdx.x;
    const int i0   = bi * 128, j0 = bj * 128;
    const int wave = tid >> 6, lane = tid & 63;
    const int wrow = wave >> 1, wcol = wave & 1;   // 2x2 waves, each 64x64
    const int m16  = lane & 15, quad = lane >> 4;

    // fragment bases in shuffled layout: row-block rb spans 16 KB (16 chunks x 1 KB);
    // frag t lives at base + t*16384, k-chunk kc at +kc*1024; lane offset lane*16.
    const char* baseA = (const char*)neb + (size_t)(i0 / 16 + wrow * 4) * 16384 + lane * 16;
    const char* baseB = (const char*)neb + (size_t)(j0 / 16 + wcol * 4) * 16384 + lane * 16;

    floatx4 zero = {0.f, 0.f, 0.f, 0.f};
    floatx4 acc[4][4];
    #pragma unroll
    for (int a = 0; a < 4; ++a)
        #pragma unroll
        for (int b = 0; b < 4; ++b) acc[a][b] = zero;

    short8 ca[4], cb[4], na[4], nb[4];
    #pragma unroll
    for (int t = 0; t < 4; ++t) {
        ca[t] = *(const short8*)(baseA + t * 16384);
        cb[t] = *(const short8*)(baseB + t * 16384);
    }

    #pragma unroll
    for (int it = 0; it < NIT; ++it) {
        if (it + 1 < NIT) {
            const int ko = (it + 1) * 1024;
            #pragma unroll
            for (int t = 0; t < 4; ++t) {
                na[t] = *(const short8*)(baseA + t * 16384 + ko);
                nb[t] = *(const short8*)(baseB + t * 16384 + ko);
            }
        }
        #pragma unroll
        for (int ti = 0; ti < 4; ++ti)
            #pragma unroll
            for (int tj = 0; tj < 4; ++tj)
                acc[ti][tj] = __builtin_amdgcn_mfma_f32_16x16x32_bf16(ca[ti], cb[tj], acc[ti][tj], 0, 0, 0);
        #pragma unroll
        for (int t = 0; t < 4; ++t) { ca[t] = na[t]; cb[t] = nb[t]; }
    }

    // row-sums: exp(2*c) summed over this block's 128 cols -> slot bj*2+wcol
    const int prow = bj * 2 + wcol;
    #pragma unroll
    for (int ti = 0; ti < 4; ++ti) {
        #pragma unroll
        for (int r = 0; r < 4; ++r) {
            float ss = 0.f;
            #pragma unroll
            for (int tj = 0; tj < 4; ++tj) ss += __expf(2.0f * acc[ti][tj][r]);
            #pragma unroll
            for (int off = 1; off < 16; off <<= 1) ss += __shfl_xor(ss, off);
            if (m16 == 0) {
                int rowg = i0 + wrow * 64 + ti * 16 + quad * 4 + r;
                partial[(size_t)prow * N + rowg] = ss;
            }
        }
    }
    // col-sums (symmetry: = row-sums of skipped tile (bj,bi)) -> slot bi*2+wrow
    if (bi < bj) {
        const int pcol = bi * 2 + wrow;
        #pragma unroll
        for (int tj = 0; tj < 4; ++tj) {
            float ss = 0.f;
            #pragma unroll
            for (int ti = 0; ti < 4; ++ti) {
                #pragma unroll
                for (int r = 0; r < 4; ++r) ss += __expf(2.0f * acc[ti][tj][r]);
            }
            ss += __shfl_xor(ss, 16);
            ss += __shfl_xor(ss, 32);
            if (quad == 0) {
                int colg = j0 + wcol * 64 + tj * 16 + m16;
                partial[(size_t)pcol * N + colg] = ss;
            }
        }
    }
}

__global__ __launch_bounds__(256) void k_final(const float* __restrict__ partial,
                                               const float* __restrict__ pos,
                                               float* __restrict__ out) {
    int tid = threadIdx.x;
    int row = blockIdx.x * 64 + (tid >> 2);
    int sub = tid & 3;
    float S = 0.f;
    #pragma unroll
    for (int i = 0; i < 32; ++i) S += partial[(size_t)(sub + i * 4) * N + row];
    S += __shfl_xor(S, 1);
    S += __shfl_xor(S, 2);
    float val = (sub == 0) ? (logf(S) - 2.0f * pos[row]) : 0.0f;
    #pragma unroll
    for (int off = 4; off < 64; off <<= 1) val += __shfl_xor(val, off);
    if ((tid & 63) == 0) atomicAdd(out, val * (1.0f / (2.0f * N)));
}

extern "C" void kernel_launch(void* const* d_in, const int* in_sizes, int n_in,
                              void* d_out, int out_size, void* d_ws, size_t ws_size,
                              hipStream_t stream) {
    const float* emb = (const float*)d_in[0];
    const float* tgt = (const float*)d_in[1];
    unsigned short* neb = (unsigned short*)d_ws;                                 // 8 MB bf16 ne (shuffled)
    float* pos     = (float*)((char*)d_ws + (size_t)N * D * 2);                  // 32 KB
    float* partial = (float*)((char*)d_ws + (size_t)N * D * 2 + (size_t)N * 4);  // 4 MB
    float* out = (float*)d_out;

    k_norm<<<N / 4, 256, 0, stream>>>(emb, tgt, neb, pos, out);
    k_gemm<<<NT * (NT + 1) / 2, 256, 0, stream>>>(neb, partial);
    k_final<<<N / 64, 256, 0, stream>>>(partial, pos, out);
}

// Round 7
// 134.002 us; speedup vs baseline: 1.6181x; 1.0321x over previous
//
#include <hip/hip_runtime.h>

// ContrastiveLoss: loss = sum_n [ log(sum_j exp(2*<ne_n,ne_j>)) - 2*<ne_n,nt_n> ] / (2N)
// N=8192, D=512.
// R6: FP8 operands. R5's pre-shuffled barrier-free GEMM with e4m3 fragments:
//     mfma_f32_16x16x32_fp8_fp8 (bf16 rate, half the fragment bytes) -> the
//     diagnosed L2-delivery bound halves. k_norm converts via v_cvt_pk_fp8_f32
//     and writes the operand-tiled layout (512 B chunk per 16-row x 32-k tile,
//     byte offset lane'*8, lane' = quad*16 + row%16). Epilogue/accum fp32.
//     XCD-partitioned triangular schedule kept from R3.

typedef __attribute__((ext_vector_type(4))) float floatx4;

#define N 8192
#define D 512
#define BK 32            // k-step in elems
#define NIT (D / BK)     // 16 k-iterations
#define NT 64            // 128-row tiles per dim

// Per-XCD segment tables: 5 segments each = [diag36, off64, off64, off64, half32].
__device__ __constant__ unsigned char seg_ga[8][5] = {
    {0,0,0,0,0},{1,1,1,1,0},{2,2,2,2,2},{3,3,3,3,2},
    {4,0,0,0,4},{5,1,1,1,4},{6,2,3,4,6},{7,4,5,5,6}};
__device__ __constant__ unsigned char seg_gb[8][5] = {
    {0,2,3,4,1},{1,2,3,4,1},{2,5,6,7,3},{3,5,6,7,3},
    {4,5,6,7,5},{5,5,6,7,5},{6,4,4,6,7},{7,7,6,7,7}};

__global__ __launch_bounds__(256) void k_norm(const float* __restrict__ emb,
                                              const float* __restrict__ tgt,
                                              unsigned char* __restrict__ neb,
                                              float* __restrict__ pos,
                                              float* __restrict__ out) {
    if (blockIdx.x == 0 && threadIdx.x == 0) *out = 0.0f;   // replaces memset dispatch
    int wave = threadIdx.x >> 6;
    int lane = threadIdx.x & 63;
    int row  = blockIdx.x * 4 + wave;          // one wave per row; lane holds k=lane*8..+8
    const float4* e4 = (const float4*)(emb + (size_t)row * D) + lane * 2;
    const float4* t4 = (const float4*)(tgt + (size_t)row * D) + lane * 2;
    float4 e0 = e4[0], e1 = e4[1];
    float4 t0 = t4[0], t1 = t4[1];
    float ee = e0.x*e0.x + e0.y*e0.y + e0.z*e0.z + e0.w*e0.w
             + e1.x*e1.x + e1.y*e1.y + e1.z*e1.z + e1.w*e1.w;
    float tt = t0.x*t0.x + t0.y*t0.y + t0.z*t0.z + t0.w*t0.w
             + t1.x*t1.x + t1.y*t1.y + t1.z*t1.z + t1.w*t1.w;
    float et = e0.x*t0.x + e0.y*t0.y + e0.z*t0.z + e0.w*t0.w
             + e1.x*t1.x + e1.y*t1.y + e1.z*t1.z + e1.w*t1.w;
    #pragma unroll
    for (int off = 1; off < 64; off <<= 1) {
        ee += __shfl_xor(ee, off);
        tt += __shfl_xor(tt, off);
        et += __shfl_xor(et, off);
    }
    float se = fmaxf(sqrtf(ee), 1e-12f);
    float st = fmaxf(sqrtf(tt), 1e-12f);
    if (lane == 0) pos[row] = et / (se * st);
    float inv = 1.0f / se;
    // pack 8 e4m3 bytes (k ascending) via HW RNE converts
    int w0 = __builtin_amdgcn_cvt_pk_fp8_f32(e0.x * inv, e0.y * inv, 0, false);
    w0     = __builtin_amdgcn_cvt_pk_fp8_f32(e0.z * inv, e0.w * inv, w0, true);
    int w1 = __builtin_amdgcn_cvt_pk_fp8_f32(e1.x * inv, e1.y * inv, 0, false);
    w1     = __builtin_amdgcn_cvt_pk_fp8_f32(e1.z * inv, e1.w * inv, w1, true);
    uint2 pk; pk.x = (unsigned)w0; pk.y = (unsigned)w1;
    // shuffled store: chunk (row>>4, lane>>2); within-chunk uint2 slot
    // (lane&3)*16 + (row&15)   [quad' = chunk-local k/8, m' = row&15]
    size_t u2idx = ((size_t)(row >> 4) * 16 + (lane >> 2)) * 64
                 + (size_t)(lane & 3) * 16 + (row & 15);
    ((uint2*)neb)[u2idx] = pk;
}

__global__ __launch_bounds__(256, 4) void k_gemm(const unsigned char* __restrict__ neb,
                                                 float* __restrict__ partial) {
    // XCD-partitioned decode: x = XCD stream, s = sequence within stream
    const int x = (int)(blockIdx.x & 7);
    int s = (int)(blockIdx.x >> 3);          // 0..259
    int seg, u;
    if (s < 36)       { seg = 0; u = s; }
    else if (s < 100) { seg = 1; u = s - 36; }
    else if (s < 164) { seg = 2; u = s - 100; }
    else if (s < 228) { seg = 3; u = s - 164; }
    else              { seg = 4; u = s - 228 + ((x & 1) ? 32 : 0); }
    const int ga = seg_ga[x][seg], gb = seg_gb[x][seg];
    int bi, bj;
    if (seg == 0) {                           // diag supertile: tri decode in 8x8
        int di = 0;
        while (u >= 8 - di) { u -= 8 - di; ++di; }
        bi = ga * 8 + di; bj = gb * 8 + di + u;
    } else {
        bi = ga * 8 + (u >> 3); bj = gb * 8 + (u & 7);
    }

    const int tid  = threadIdx.x;
    const int i0   = bi * 128, j0 = bj * 128;
    const int wave = tid >> 6, lane = tid & 63;
    const int wrow = wave >> 1, wcol = wave & 1;   // 2x2 waves, each 64x64
    const int m16  = lane & 15, quad = lane >> 4;

    // fragment bases in shuffled fp8 layout: 16-row block spans 8 KB
    // (16 k-chunks x 512 B); frag t at +t*8192, k-chunk it at +it*512;
    // lane offset lane*8 (wave covers contiguous 512 B -> coalesced dwordx2).
    const char* baseA = (const char*)neb + (size_t)(i0 / 16 + wrow * 4) * 8192 + lane * 8;
    const char* baseB = (const char*)neb + (size_t)(j0 / 16 + wcol * 4) * 8192 + lane * 8;

    floatx4 zero = {0.f, 0.f, 0.f, 0.f};
    floatx4 acc[4][4];
    #pragma unroll
    for (int a = 0; a < 4; ++a)
        #pragma unroll
        for (int b = 0; b < 4; ++b) acc[a][b] = zero;

    long ca[4], cb[4], na[4], nb[4];
    #pragma unroll
    for (int t = 0; t < 4; ++t) {
        ca[t] = *(const long*)(baseA + t * 8192);
        cb[t] = *(const long*)(baseB + t * 8192);
    }

    #pragma unroll
    for (int it = 0; it < NIT; ++it) {
        if (it + 1 < NIT) {
            const int ko = (it + 1) * 512;
            #pragma unroll
            for (int t = 0; t < 4; ++t) {
                na[t] = *(const long*)(baseA + t * 8192 + ko);
                nb[t] = *(const long*)(baseB + t * 8192 + ko);
            }
        }
        #pragma unroll
        for (int ti = 0; ti < 4; ++ti)
            #pragma unroll
            for (int tj = 0; tj < 4; ++tj)
                acc[ti][tj] = __builtin_amdgcn_mfma_f32_16x16x32_fp8_fp8(ca[ti], cb[tj], acc[ti][tj], 0, 0, 0);
        #pragma unroll
        for (int t = 0; t < 4; ++t) { ca[t] = na[t]; cb[t] = nb[t]; }
    }

    // row-sums: exp(2*c) summed over this block's 128 cols -> slot bj*2+wcol
    const int prow = bj * 2 + wcol;
    #pragma unroll
    for (int ti = 0; ti < 4; ++ti) {
        #pragma unroll
        for (int r = 0; r < 4; ++r) {
            float ss = 0.f;
            #pragma unroll
            for (int tj = 0; tj < 4; ++tj) ss += __expf(2.0f * acc[ti][tj][r]);
            #pragma unroll
            for (int off = 1; off < 16; off <<= 1) ss += __shfl_xor(ss, off);
            if (m16 == 0) {
                int rowg = i0 + wrow * 64 + ti * 16 + quad * 4 + r;
                partial[(size_t)prow * N + rowg] = ss;
            }
        }
    }
    // col-sums (symmetry: = row-sums of skipped tile (bj,bi)) -> slot bi*2+wrow
    if (bi < bj) {
        const int pcol = bi * 2 + wrow;
        #pragma unroll
        for (int tj = 0; tj < 4; ++tj) {
            float ss = 0.f;
            #pragma unroll
            for (int ti = 0; ti < 4; ++ti) {
                #pragma unroll
                for (int r = 0; r < 4; ++r) ss += __expf(2.0f * acc[ti][tj][r]);
            }
            ss += __shfl_xor(ss, 16);
            ss += __shfl_xor(ss, 32);
            if (quad == 0) {
                int colg = j0 + wcol * 64 + tj * 16 + m16;
                partial[(size_t)pcol * N + colg] = ss;
            }
        }
    }
}

__global__ __launch_bounds__(256) void k_final(const float* __restrict__ partial,
                                               const float* __restrict__ pos,
                                               float* __restrict__ out) {
    int tid = threadIdx.x;
    int row = blockIdx.x * 64 + (tid >> 2);
    int sub = tid & 3;
    float S = 0.f;
    #pragma unroll
    for (int i = 0; i < 32; ++i) S += partial[(size_t)(sub + i * 4) * N + row];
    S += __shfl_xor(S, 1);
    S += __shfl_xor(S, 2);
    float val = (sub == 0) ? (logf(S) - 2.0f * pos[row]) : 0.0f;
    #pragma unroll
    for (int off = 4; off < 64; off <<= 1) val += __shfl_xor(val, off);
    if ((tid & 63) == 0) atomicAdd(out, val * (1.0f / (2.0f * N)));
}

extern "C" void kernel_launch(void* const* d_in, const int* in_sizes, int n_in,
                              void* d_out, int out_size, void* d_ws, size_t ws_size,
                              hipStream_t stream) {
    const float* emb = (const float*)d_in[0];
    const float* tgt = (const float*)d_in[1];
    unsigned char* neb = (unsigned char*)d_ws;                                   // 4 MB fp8 ne (shuffled)
    float* pos     = (float*)((char*)d_ws + (size_t)N * D);                      // 32 KB
    float* partial = (float*)((char*)d_ws + (size_t)N * D + (size_t)N * 4);      // 4 MB
    float* out = (float*)d_out;

    k_norm<<<N / 4, 256, 0, stream>>>(emb, tgt, neb, pos, out);
    k_gemm<<<NT * (NT + 1) / 2, 256, 0, stream>>>(neb, partial);
    k_final<<<N / 64, 256, 0, stream>>>(partial, pos, out);
}

// Round 8
// 116.312 us; speedup vs baseline: 1.8642x; 1.1521x over previous
//
#include <hip/hip_runtime.h>

// ContrastiveLoss: loss = sum_n [ log(sum_j exp(2*<ne_n,ne_j>)) - 2*<ne_n,nt_n> ] / (2N)
// N=8192, D=512.
// R7: PAIR-INTERLEAVED fp8 operand layout -- one dwordx4 (16 B/lane) load
//     carries TWO k-chunks of a fragment, doubling the prefetch window
//     (~620 cyc own-MFMA issue) and halving VMEM instruction / waitcnt count.
//     Within-pair MFMA order: 16 lo-chunk then 16 hi-chunk (16 independent ops
//     between dependent accumulates). Barrier-free K-loop, XCD-partitioned
//     triangular schedule, fp32 epilogue -- all unchanged from R6.

typedef __attribute__((ext_vector_type(4))) float floatx4;
typedef __attribute__((ext_vector_type(2))) long long2v;

#define N 8192
#define D 512
#define NPAIR 8          // 8 pairs x 64 k = 512
#define NT 64            // 128-row tiles per dim

// Per-XCD segment tables: 5 segments each = [diag36, off64, off64, off64, half32].
__device__ __constant__ unsigned char seg_ga[8][5] = {
    {0,0,0,0,0},{1,1,1,1,0},{2,2,2,2,2},{3,3,3,3,2},
    {4,0,0,0,4},{5,1,1,1,4},{6,2,3,4,6},{7,4,5,5,6}};
__device__ __constant__ unsigned char seg_gb[8][5] = {
    {0,2,3,4,1},{1,2,3,4,1},{2,5,6,7,3},{3,5,6,7,3},
    {4,5,6,7,5},{5,5,6,7,5},{6,4,4,6,7},{7,7,6,7,7}};

__global__ __launch_bounds__(256) void k_norm(const float* __restrict__ emb,
                                              const float* __restrict__ tgt,
                                              unsigned char* __restrict__ neb,
                                              float* __restrict__ pos,
                                              float* __restrict__ out) {
    if (blockIdx.x == 0 && threadIdx.x == 0) *out = 0.0f;   // replaces memset dispatch
    int wave = threadIdx.x >> 6;
    int lane = threadIdx.x & 63;
    int row  = blockIdx.x * 4 + wave;          // one wave per row; lane holds k=lane*8..+8
    const float4* e4 = (const float4*)(emb + (size_t)row * D) + lane * 2;
    const float4* t4 = (const float4*)(tgt + (size_t)row * D) + lane * 2;
    float4 e0 = e4[0], e1 = e4[1];
    float4 t0 = t4[0], t1 = t4[1];
    float ee = e0.x*e0.x + e0.y*e0.y + e0.z*e0.z + e0.w*e0.w
             + e1.x*e1.x + e1.y*e1.y + e1.z*e1.z + e1.w*e1.w;
    float tt = t0.x*t0.x + t0.y*t0.y + t0.z*t0.z + t0.w*t0.w
             + t1.x*t1.x + t1.y*t1.y + t1.z*t1.z + t1.w*t1.w;
    float et = e0.x*t0.x + e0.y*t0.y + e0.z*t0.z + e0.w*t0.w
             + e1.x*t1.x + e1.y*t1.y + e1.z*t1.z + e1.w*t1.w;
    #pragma unroll
    for (int off = 1; off < 64; off <<= 1) {
        ee += __shfl_xor(ee, off);
        tt += __shfl_xor(tt, off);
        et += __shfl_xor(et, off);
    }
    float se = fmaxf(sqrtf(ee), 1e-12f);
    float st = fmaxf(sqrtf(tt), 1e-12f);
    if (lane == 0) pos[row] = et / (se * st);
    float inv = 1.0f / se;
    // pack 8 e4m3 bytes (k ascending) via HW RNE converts
    int w0 = __builtin_amdgcn_cvt_pk_fp8_f32(e0.x * inv, e0.y * inv, 0, false);
    w0     = __builtin_amdgcn_cvt_pk_fp8_f32(e0.z * inv, e0.w * inv, w0, true);
    int w1 = __builtin_amdgcn_cvt_pk_fp8_f32(e1.x * inv, e1.y * inv, 0, false);
    w1     = __builtin_amdgcn_cvt_pk_fp8_f32(e1.z * inv, e1.w * inv, w1, true);
    uint2 pk; pk.x = (unsigned)w0; pk.y = (unsigned)w1;
    // pair-interleaved shuffled store:
    // rb = row>>4 (8 KB block), pair p = lane>>3 (1 KB), chunk parity
    // par = (lane>>2)&1, q' = lane&3, m = row&15.
    // uint2 slot = p*128 + (q'*16+m)*2 + par  ->  k_gemm lane (q,m) reads
    // 16 B at p*1024 + (q*16+m)*16 = [chunk 2p | chunk 2p+1] fragment data.
    size_t u2idx = (size_t)(row >> 4) * 1024
                 + (size_t)(lane >> 3) * 128
                 + (size_t)((lane & 3) * 16 + (row & 15)) * 2
                 + ((lane >> 2) & 1);
    ((uint2*)neb)[u2idx] = pk;
}

__global__ __launch_bounds__(256, 3) void k_gemm(const unsigned char* __restrict__ neb,
                                                 float* __restrict__ partial) {
    // XCD-partitioned decode: x = XCD stream, s = sequence within stream
    const int x = (int)(blockIdx.x & 7);
    int s = (int)(blockIdx.x >> 3);          // 0..259
    int seg, u;
    if (s < 36)       { seg = 0; u = s; }
    else if (s < 100) { seg = 1; u = s - 36; }
    else if (s < 164) { seg = 2; u = s - 100; }
    else if (s < 228) { seg = 3; u = s - 164; }
    else              { seg = 4; u = s - 228 + ((x & 1) ? 32 : 0); }
    const int ga = seg_ga[x][seg], gb = seg_gb[x][seg];
    int bi, bj;
    if (seg == 0) {                           // diag supertile: tri decode in 8x8
        int di = 0;
        while (u >= 8 - di) { u -= 8 - di; ++di; }
        bi = ga * 8 + di; bj = gb * 8 + di + u;
    } else {
        bi = ga * 8 + (u >> 3); bj = gb * 8 + (u & 7);
    }

    const int tid  = threadIdx.x;
    const int i0   = bi * 128, j0 = bj * 128;
    const int wave = tid >> 6, lane = tid & 63;
    const int wrow = wave >> 1, wcol = wave & 1;   // 2x2 waves, each 64x64
    const int m16  = lane & 15, quad = lane >> 4;

    // fragment bases: 16-row block spans 8 KB (8 pairs x 1 KB); frag t at
    // +t*8192, pair p at +p*1024; lane offset lane*16 (contiguous 1 KB/wave).
    const char* baseA = (const char*)neb + (size_t)(i0 / 16 + wrow * 4) * 8192 + lane * 16;
    const char* baseB = (const char*)neb + (size_t)(j0 / 16 + wcol * 4) * 8192 + lane * 16;

    floatx4 zero = {0.f, 0.f, 0.f, 0.f};
    floatx4 acc[4][4];
    #pragma unroll
    for (int a = 0; a < 4; ++a)
        #pragma unroll
        for (int b = 0; b < 4; ++b) acc[a][b] = zero;

    long2v ca[4], cb[4], na[4], nb[4];
    #pragma unroll
    for (int t = 0; t < 4; ++t) {
        ca[t] = *(const long2v*)(baseA + t * 8192);
        cb[t] = *(const long2v*)(baseB + t * 8192);
    }

    #pragma unroll
    for (int p = 0; p < NPAIR; ++p) {
        if (p + 1 < NPAIR) {
            const int ko = (p + 1) * 1024;
            #pragma unroll
            for (int t = 0; t < 4; ++t) {
                na[t] = *(const long2v*)(baseA + t * 8192 + ko);
                nb[t] = *(const long2v*)(baseB + t * 8192 + ko);
            }
        }
        #pragma unroll
        for (int ti = 0; ti < 4; ++ti)
            #pragma unroll
            for (int tj = 0; tj < 4; ++tj)
                acc[ti][tj] = __builtin_amdgcn_mfma_f32_16x16x32_fp8_fp8(ca[ti][0], cb[tj][0], acc[ti][tj], 0, 0, 0);
        #pragma unroll
        for (int ti = 0; ti < 4; ++ti)
            #pragma unroll
            for (int tj = 0; tj < 4; ++tj)
                acc[ti][tj] = __builtin_amdgcn_mfma_f32_16x16x32_fp8_fp8(ca[ti][1], cb[tj][1], acc[ti][tj], 0, 0, 0);
        #pragma unroll
        for (int t = 0; t < 4; ++t) { ca[t] = na[t]; cb[t] = nb[t]; }
    }

    // row-sums: exp(2*c) summed over this block's 128 cols -> slot bj*2+wcol
    const int prow = bj * 2 + wcol;
    #pragma unroll
    for (int ti = 0; ti < 4; ++ti) {
        #pragma unroll
        for (int r = 0; r < 4; ++r) {
            float ss = 0.f;
            #pragma unroll
            for (int tj = 0; tj < 4; ++tj) ss += __expf(2.0f * acc[ti][tj][r]);
            #pragma unroll
            for (int off = 1; off < 16; off <<= 1) ss += __shfl_xor(ss, off);
            if (m16 == 0) {
                int rowg = i0 + wrow * 64 + ti * 16 + quad * 4 + r;
                partial[(size_t)prow * N + rowg] = ss;
            }
        }
    }
    // col-sums (symmetry: = row-sums of skipped tile (bj,bi)) -> slot bi*2+wrow
    if (bi < bj) {
        const int pcol = bi * 2 + wrow;
        #pragma unroll
        for (int tj = 0; tj < 4; ++tj) {
            float ss = 0.f;
            #pragma unroll
            for (int ti = 0; ti < 4; ++ti) {
                #pragma unroll
                for (int r = 0; r < 4; ++r) ss += __expf(2.0f * acc[ti][tj][r]);
            }
            ss += __shfl_xor(ss, 16);
            ss += __shfl_xor(ss, 32);
            if (quad == 0) {
                int colg = j0 + wcol * 64 + tj * 16 + m16;
                partial[(size_t)pcol * N + colg] = ss;
            }
        }
    }
}

__global__ __launch_bounds__(256) void k_final(const float* __restrict__ partial,
                                               const float* __restrict__ pos,
                                               float* __restrict__ out) {
    int tid = threadIdx.x;
    int row = blockIdx.x * 64 + (tid >> 2);
    int sub = tid & 3;
    float S = 0.f;
    #pragma unroll
    for (int i = 0; i < 32; ++i) S += partial[(size_t)(sub + i * 4) * N + row];
    S += __shfl_xor(S, 1);
    S += __shfl_xor(S, 2);
    float val = (sub == 0) ? (logf(S) - 2.0f * pos[row]) : 0.0f;
    #pragma unroll
    for (int off = 4; off < 64; off <<= 1) val += __shfl_xor(val, off);
    if ((tid & 63) == 0) atomicAdd(out, val * (1.0f / (2.0f * N)));
}

extern "C" void kernel_launch(void* const* d_in, const int* in_sizes, int n_in,
                              void* d_out, int out_size, void* d_ws, size_t ws_size,
                              hipStream_t stream) {
    const float* emb = (const float*)d_in[0];
    const float* tgt = (const float*)d_in[1];
    unsigned char* neb = (unsigned char*)d_ws;                                   // 4 MB fp8 ne (pair-shuffled)
    float* pos     = (float*)((char*)d_ws + (size_t)N * D);                      // 32 KB
    float* partial = (float*)((char*)d_ws + (size_t)N * D + (size_t)N * 4);      // 4 MB
    float* out = (float*)d_out;

    k_norm<<<N / 4, 256, 0, stream>>>(emb, tgt, neb, pos, out);
    k_gemm<<<NT * (NT + 1) / 2, 256, 0, stream>>>(neb, partial);
    k_final<<<N / 64, 256, 0, stream>>>(partial, pos, out);
}